// Round 7
// baseline (73.050 us; speedup 1.0000x reference)
//
#include <hip/hip_runtime.h>

typedef float f4v __attribute__((ext_vector_type(4)));
typedef float f32x4 __attribute__((ext_vector_type(4)));
typedef __bf16 bf16x8 __attribute__((ext_vector_type(8)));
typedef __bf16 bf16x4 __attribute__((ext_vector_type(4)));
typedef unsigned short ushort8 __attribute__((ext_vector_type(8)));

static constexpr int KDIM = 2048;

// workspace layout (bytes)
static constexpr size_t OFF_XN      = 0;                                     // ushort [3][256][2048]  (3 MB)
static constexpr size_t OFF_PART    = (size_t)3 * 256 * 2048 * 2;            // float  [768][256][4]   (3 MB)
static constexpr size_t OFF_DOTT    = OFF_PART + (size_t)768 * 256 * 16;     // float  [768]
static constexpr size_t OFF_ROWLOSS = OFF_DOTT + 768 * 4;                    // float  [768]

__device__ __forceinline__ unsigned short f2bf(float x) {
  union { float f; unsigned u; } c; c.f = x;
  unsigned r = c.u + 0x7fffu + ((c.u >> 16) & 1u);   // RNE
  return (unsigned short)(r >> 16);
}

__device__ __forceinline__ void gload_lds16(const void* g, void* l) {
  __builtin_amdgcn_global_load_lds((const __attribute__((address_space(1))) void*)g,
                                   (__attribute__((address_space(3))) void*)l,
                                   16, 0, 0);
}

// f32x4 -> bf16x4 (v_cvt_pk_bf16_f32 pair) -> 8B LDS store
__device__ __forceinline__ void cvt_store8(char* p, f4v v) {
  bf16x4 o;
  o[0] = (__bf16)v[0]; o[1] = (__bf16)v[1]; o[2] = (__bf16)v[2]; o[3] = (__bf16)v[3];
  *(bf16x4*)p = o;
}

// ---------------- kernel 1: row-normalize inputs -> bf16 ----------------
__global__ __launch_bounds__(256) void k_normalize(
    const float* __restrict__ x0, const float* __restrict__ x1, const float* __restrict__ x2,
    unsigned short* __restrict__ xn)
{
  int bid = blockIdx.x;            // 0..767 : branch*256 + row
  int branch = bid >> 8;
  int row = bid & 255;
  const float* src = (branch == 0 ? x0 : (branch == 1 ? x1 : x2)) + (size_t)row * KDIM;
  int tid = threadIdx.x;
  f4v a = *(const f4v*)(src + tid * 8);
  f4v b = *(const f4v*)(src + tid * 8 + 4);
  float s = a[0]*a[0] + a[1]*a[1] + a[2]*a[2] + a[3]*a[3]
          + b[0]*b[0] + b[1]*b[1] + b[2]*b[2] + b[3]*b[3];
  #pragma unroll
  for (int m = 1; m < 64; m <<= 1) s += __shfl_xor(s, m);
  __shared__ float ls[4];
  if ((tid & 63) == 0) ls[tid >> 6] = s;
  __syncthreads();
  float total = ls[0] + ls[1] + ls[2] + ls[3];
  float inv = 1.0f / fmaxf(sqrtf(total), 1e-12f);
  ushort8 u;
  #pragma unroll
  for (int e = 0; e < 4; ++e) u[e]     = f2bf(a[e] * inv);
  #pragma unroll
  for (int e = 0; e < 4; ++e) u[4 + e] = f2bf(b[e] * inv);
  *(ushort8*)(xn + (size_t)bid * KDIM + tid * 8) = u;
}

// ---------------- kernel 2: fused GEMM + per-tile reductions ----------------
// BM=128, BN=64, BK=64. Grid = 768. 4 waves (2M x 2N), each 64x32.
// Period-3 deep pipeline:
//   A: 3-deep LDS ring, STAGE_A(p+2) via global_load_lds   (~2 phases slack, L2-hit)
//   B: 3 reg sets, LOADB(p+3) (~2.5 phases slack, HBM) -> cvt -> WRITE_B(p+1) AFTER compute
// Issue order per phase: SA, LB (pinned) -> in-order retire means the single
// explicit vmcnt(12) at phase end retires exactly SA(p+1); never drains below 12.
__global__ __launch_bounds__(256, 2) void k_gemm_fused(
    const unsigned short* __restrict__ xn,
    const float* __restrict__ f0, const float* __restrict__ f1, const float* __restrict__ f2,
    const int* __restrict__ targets,
    float* __restrict__ part, float* __restrict__ dotT)
{
  // A: 3 x 16 KiB at 0 / 16384 / 32768 ; B: 3 x 8 KiB at 49152 + slot*8192
  __shared__ char lds[73728];

  int bid = blockIdx.x;
  int swz = (bid & 7) * 96 + (bid >> 3);   // XCD-aware, 768 % 8 == 0 -> bijective
  int branch = swz >> 8;
  int ntile = (swz & 255) >> 1;            // 128 n-tiles of 64 cols
  int mtile = swz & 1;                     // mtile siblings adjacent -> same XCD L2 shares B

  const unsigned short* A = xn + ((size_t)branch * 256 + (size_t)mtile * 128) * KDIM;
  const float* F = (branch == 0 ? f0 : (branch == 1 ? f1 : f2)) + (size_t)ntile * 64 * KDIM;

  int tid = threadIdx.x;
  int wave = tid >> 6;
  int lane = tid & 63;
  int rcol0 = lane & 15;
  int klane = lane >> 4;
  int wr = wave >> 1;    // M quadrant
  int wc = wave & 1;     // N quadrant

  // ---- A staging (source pre-swizzled, linear LDS dest)
  const unsigned short* aSrc = A + (size_t)(tid >> 3) * KDIM
                             + (((tid & 7) ^ ((tid >> 3) & 7)) << 3);
  char* aDst = lds + wave * 1024;

#define STAGE_A(kt, slot) do { \
    _Pragma("unroll") for (int g = 0; g < 4; ++g) \
      gload_lds16(aSrc + (size_t)g * 32 * KDIM + (kt) * 64, \
                  aDst + (slot) * 16384 + g * 4096); \
  } while (0)

  // ---- B global loads: row = g*16 + (tid>>4), 16B chunk = tid&15
  const float* bSrc = F + (size_t)(tid >> 4) * KDIM + (tid & 15) * 4;
  f4v bA0, bA1, bA2, bA3, bB0, bB1, bB2, bB3, bC0, bC1, bC2, bC3;

#define LOADB_G(kt, R) do { \
    R##0 = *(const f4v*)(bSrc + (kt) * 64); \
    R##1 = *(const f4v*)(bSrc + 16 * KDIM + (kt) * 64); \
    R##2 = *(const f4v*)(bSrc + 32 * KDIM + (kt) * 64); \
    R##3 = *(const f4v*)(bSrc + 48 * KDIM + (kt) * 64); \
  } while (0)

  // ---- B LDS write addressing (swizzled; bank-conflict-free, measured r5/r6)
  int bOff = (tid >> 4) * 128
           + (((((tid & 15) >> 1)) ^ ((tid >> 4) & 7)) << 4) + (tid & 1) * 8;

#define WRITE_B(R, slot) do { \
    char* wb = lds + 49152 + (slot) * 8192 + bOff; \
    cvt_store8(wb,        R##0); \
    cvt_store8(wb + 2048, R##1); \
    cvt_store8(wb + 4096, R##2); \
    cvt_store8(wb + 6144, R##3); \
  } while (0)

  f32x4 acc[4][2];
  #pragma unroll
  for (int i = 0; i < 4; ++i)
    #pragma unroll
    for (int j = 0; j < 2; ++j)
      #pragma unroll
      for (int q = 0; q < 4; ++q) acc[i][j][q] = 0.0f;

  int sa = rcol0 & 7;
  int aRdOff = (wr * 64 + rcol0) * 128;
  int bRdOff = (wc * 32 + rcol0) * 128;

#define COMPUTE(slot) do { \
    const char* ra = lds + (slot) * 16384 + aRdOff; \
    const char* rb = lds + 49152 + (slot) * 8192 + bRdOff; \
    _Pragma("unroll") for (int ks = 0; ks < 2; ++ks) { \
      int ch = (((ks * 4 + klane) ^ sa) << 4); \
      bf16x8 b0 = *(const bf16x8*)(rb + ch); \
      bf16x8 b1 = *(const bf16x8*)(rb + 2048 + ch); \
      bf16x8 a0 = *(const bf16x8*)(ra + ch); \
      bf16x8 a1 = *(const bf16x8*)(ra + 2048 + ch); \
      bf16x8 a2 = *(const bf16x8*)(ra + 4096 + ch); \
      bf16x8 a3 = *(const bf16x8*)(ra + 6144 + ch); \
      acc[0][0] = __builtin_amdgcn_mfma_f32_16x16x32_bf16(a0, b0, acc[0][0], 0, 0, 0); \
      acc[0][1] = __builtin_amdgcn_mfma_f32_16x16x32_bf16(a0, b1, acc[0][1], 0, 0, 0); \
      acc[1][0] = __builtin_amdgcn_mfma_f32_16x16x32_bf16(a1, b0, acc[1][0], 0, 0, 0); \
      acc[1][1] = __builtin_amdgcn_mfma_f32_16x16x32_bf16(a1, b1, acc[1][1], 0, 0, 0); \
      acc[2][0] = __builtin_amdgcn_mfma_f32_16x16x32_bf16(a2, b0, acc[2][0], 0, 0, 0); \
      acc[2][1] = __builtin_amdgcn_mfma_f32_16x16x32_bf16(a2, b1, acc[2][1], 0, 0, 0); \
      acc[3][0] = __builtin_amdgcn_mfma_f32_16x16x32_bf16(a3, b0, acc[3][0], 0, 0, 0); \
      acc[3][1] = __builtin_amdgcn_mfma_f32_16x16x32_bf16(a3, b1, acc[3][1], 0, 0, 0); \
    } \
  } while (0)

#define PHASE_END(vm) do { \
    asm volatile("s_waitcnt vmcnt(" #vm ") lgkmcnt(0)" ::: "memory"); \
    __builtin_amdgcn_s_barrier(); \
    __builtin_amdgcn_sched_barrier(0); \
  } while (0)

  // steady phase p: SA(p+2)->A[(p+2)%3]; LB(p+3)->regs[(p+3)%3]; COMPUTE(p);
  //                 WB(p+1): regs[(p+1)%3]->B[(p+1)%3]; vmcnt(12)+barrier
#define PHASE_FULL(kt, SA_SLOT, LB_R, C_SLOT, WB_R, WB_SLOT) do { \
    STAGE_A((kt) + 2, SA_SLOT); \
    __builtin_amdgcn_sched_barrier(0); \
    LOADB_G((kt) + 3, LB_R); \
    __builtin_amdgcn_sched_barrier(0); \
    COMPUTE(C_SLOT); \
    WRITE_B(WB_R, WB_SLOT); \
    PHASE_END(12); \
  } while (0)

  // prologue: A(0),A(1) staged; B(0..2) issued; B(0) written (implicit wait retires SA0/SA1)
  STAGE_A(0, 0);
  STAGE_A(1, 1);
  __builtin_amdgcn_sched_barrier(0);
  LOADB_G(0, bA);
  LOADB_G(1, bB);
  LOADB_G(2, bC);
  __builtin_amdgcn_sched_barrier(0);
  WRITE_B(bA, 0);
  PHASE_END(8);

  #pragma unroll 1
  for (int t = 0; t < 27; t += 3) {
    PHASE_FULL(t,     2, bA, 0, bB, 1);   // p%3==0
    PHASE_FULL(t + 1, 0, bB, 1, bC, 2);   // p%3==1
    PHASE_FULL(t + 2, 1, bC, 2, bA, 0);   // p%3==2
  }
  PHASE_FULL(27, 2, bA, 0, bB, 1);        // p=27: SA(29), LB(30)
  PHASE_FULL(28, 0, bB, 1, bC, 2);        // p=28: SA(30), LB(31)
  // p=29: SA(31)->A[1]; COMPUTE(29)=slot2; WB(30): bA->B[0]
  STAGE_A(31, 1);
  __builtin_amdgcn_sched_barrier(0);
  COMPUTE(2);
  WRITE_B(bA, 0);
  PHASE_END(8);
  // p=30: COMPUTE(30)=slot0; WB(31): bB->B[1]
  COMPUTE(0);
  WRITE_B(bB, 1);
  PHASE_END(0);
  // p=31
  COMPUTE(1);

#undef STAGE_A
#undef LOADB_G
#undef WRITE_B
#undef COMPUTE
#undef PHASE_END
#undef PHASE_FULL

  // fused epilogue: per-row partials over this wave's 32-col span.
  // p1 = sum exp(20d-20), Z1 = sum exp(D-2), Z2 = sum exp(2(D-2)), Z3 = sum exp(3(D-2))
  // D = sqrt(max(2-2d,0)).  C/D layout: col = lane&15, row = klane*4 + q.
  int tbase = branch * 256;
  int mbase = mtile * 128;
  #pragma unroll
  for (int i = 0; i < 4; ++i) {
    #pragma unroll
    for (int q = 0; q < 4; ++q) {
      int row = mbase + wr * 64 + i * 16 + (klane << 2) + q;   // row in [0,256)
      int tgt = targets[row];
      float s1 = 0.f, s2 = 0.f, s3 = 0.f, s4 = 0.f;
      #pragma unroll
      for (int j = 0; j < 2; ++j) {
        float d = acc[i][j][q];
        float e1 = __expf(fmaf(20.0f, d, -20.0f));
        float Dv = sqrtf(fmaxf(2.0f - 2.0f * d, 0.0f));
        float e2 = __expf(Dv - 2.0f);
        s1 += e1; s2 += e2;
        float t2 = e2 * e2;
        s3 += t2; s4 += t2 * e2;
        int col = ntile * 64 + wc * 32 + j * 16 + rcol0;
        if (col == tgt) dotT[tbase + row] = d;   // exactly one writer per row globally
      }
      #pragma unroll
      for (int m = 1; m < 16; m <<= 1) {         // reduce across 16 lanes sharing this row
        s1 += __shfl_xor(s1, m);
        s2 += __shfl_xor(s2, m);
        s3 += __shfl_xor(s3, m);
        s4 += __shfl_xor(s4, m);
      }
      if (rcol0 == 0) {
        f32x4 p; p[0] = s1; p[1] = s2; p[2] = s3; p[3] = s4;
        *(f32x4*)(part + ((size_t)(tbase + row) * 256 + ntile * 2 + wc) * 4) = p;
      }
    }
  }
}

// ---------------- kernel 3: combine 256 tile-partials per row -> row loss ----------------
__global__ __launch_bounds__(256) void k_combine(
    const float* __restrict__ part, const float* __restrict__ dotT, float* __restrict__ rowloss)
{
  int row = blockIdx.x;    // 0..767
  int tid = threadIdx.x;   // 256
  f4v p = *(const f4v*)(part + ((size_t)row * 256 + tid) * 4);
  float a0 = p[0], a1 = p[1], a2 = p[2], a3 = p[3];
  #pragma unroll
  for (int m = 1; m < 64; m <<= 1) {
    a0 += __shfl_xor(a0, m); a1 += __shfl_xor(a1, m);
    a2 += __shfl_xor(a2, m); a3 += __shfl_xor(a3, m);
  }
  __shared__ float ls[4][4];
  if ((tid & 63) == 0) {
    int w = tid >> 6;
    ls[0][w] = a0; ls[1][w] = a1; ls[2][w] = a2; ls[3][w] = a3;
  }
  __syncthreads();
  if (tid == 0) {
    float p1 = ls[0][0] + ls[0][1] + ls[0][2] + ls[0][3];
    float Z1 = ls[1][0] + ls[1][1] + ls[1][2] + ls[1][3];
    float Z2 = ls[2][0] + ls[2][1] + ls[2][2] + ls[2][3];
    float Z3 = ls[3][0] + ls[3][1] + ls[3][2] + ls[3][3];
    float dt = dotT[row];
    // CE1 = logsumexp(20*dot) - 20*dot_t   (fixed shift 20 is exact: 20d-20 <= 0)
    float CE1 = 20.0f + logf(p1) - 20.0f * dt;
    // CE2 = log(sum_n exp(S_n)) - S_t ;  sum_n exp(S_n) = N + 1 + Z2/(2 Z1^2) + Z3/(6 Z1^3)
    float Dt = sqrtf(fmaxf(2.0f - 2.0f * dt, 0.0f));
    float St = __expf(Dt - 2.0f) / Z1;
    float sES = 8193.0f + Z2 / (2.0f * Z1 * Z1) + Z3 / (6.0f * Z1 * Z1 * Z1);
    float CE2 = logf(sES) - St;
    rowloss[row] = (CE1 + CE2) * (0.5f / 256.0f);
  }
}

// ---------------- kernel 4: final sum ----------------
__global__ __launch_bounds__(256) void k_final(const float* __restrict__ rowloss, float* __restrict__ out)
{
  int tid = threadIdx.x;
  float v = rowloss[tid] + rowloss[tid + 256] + rowloss[tid + 512];
  #pragma unroll
  for (int m = 1; m < 64; m <<= 1) v += __shfl_xor(v, m);
  __shared__ float ls[4];
  if ((tid & 63) == 0) ls[tid >> 6] = v;
  __syncthreads();
  if (tid == 0) out[0] = ls[0] + ls[1] + ls[2] + ls[3];
}

extern "C" void kernel_launch(void* const* d_in, const int* in_sizes, int n_in,
                              void* d_out, int out_size, void* d_ws, size_t ws_size,
                              hipStream_t stream) {
  const float* in0 = (const float*)d_in[0];
  const float* in1 = (const float*)d_in[1];
  const float* in2 = (const float*)d_in[2];
  const int* targets = (const int*)d_in[3];
  // d_in[4] = epoch (unused by the loss)
  const float* f0 = (const float*)d_in[5];
  const float* f1 = (const float*)d_in[6];
  const float* f2 = (const float*)d_in[7];

  char* ws = (char*)d_ws;
  unsigned short* xn = (unsigned short*)(ws + OFF_XN);
  float* part    = (float*)(ws + OFF_PART);
  float* dotT    = (float*)(ws + OFF_DOTT);
  float* rowloss = (float*)(ws + OFF_ROWLOSS);
  float* out = (float*)d_out;

  k_normalize<<<768, 256, 0, stream>>>(in0, in1, in2, xn);
  k_gemm_fused<<<768, 256, 0, stream>>>(xn, f0, f1, f2, targets, part, dotT);
  k_combine<<<768, 256, 0, stream>>>(part, dotT, rowloss);
  k_final<<<1, 256, 0, stream>>>(rowloss, out);
}